// Round 1
// baseline (652.455 us; speedup 1.0000x reference)
//
#include <hip/hip_runtime.h>

#define B_ 64
#define D_ 256
#define T_ 1024
#define NC_ 1024
#define DT_ (D_ * T_)              // 262144
#define NPTS_ (B_ * T_)            // 65536

#define QSZ_   16777216            // B*D*T
#define LOSS_OFF 16777216
#define CMT_OFF  16777217
#define IDX_OFF  16777218
#define PERP_OFF 16842754

// ---------------- Kernel A: transpose embed + fp64 code norms ----------------
__global__ void prep_kernel(const float* __restrict__ embed,
                            float* __restrict__ embedT,
                            double* __restrict__ norms) {
  int j = blockIdx.x;        // code index, 1024 blocks
  int d = threadIdx.x;       // 256 threads
  float v = embed[(size_t)j * D_ + d];
  embedT[(size_t)d * NC_ + j] = v;
  double s = (double)v * (double)v;
  for (int m = 32; m; m >>= 1) s += __shfl_down(s, m, 64);
  __shared__ double red[4];
  if ((d & 63) == 0) red[d >> 6] = s;
  __syncthreads();
  if (d == 0) norms[j] = red[0] + red[1] + red[2] + red[3];
}

// ---------------- Kernel B: distance GEMM + argmin --------------------------
// Block: 256 threads, 64 points (one b, 64 consecutive t) x all 1024 codes.
// Register tile 4 points x 8 codes; K staged in 16-d chunks of embedT in LDS.
__global__ __launch_bounds__(256, 2) void argmin_kernel(
    const float* __restrict__ inputs, const float* __restrict__ embedT,
    const double* __restrict__ norms, float* __restrict__ idx_out,
    int* __restrict__ counts) {
  __shared__ float xs[256 * 64];   // [d][p]  64 KB
  __shared__ float es[16 * 128];   // [dd][c]  8 KB
  __shared__ double xn2[64];

  int tid = threadIdx.x;
  int bx = blockIdx.x;             // 1024 blocks
  int b = bx >> 4;
  int t0 = (bx & 15) * 64;
  const float* xin = inputs + (size_t)b * DT_ + t0;

  // stage x tile [256 d][64 p], coalesced along t
#pragma unroll 4
  for (int i = 0; i < 64; ++i) {
    int fl = i * 256 + tid;
    int d = fl >> 6;
    int p = fl & 63;
    xs[d * 64 + p] = xin[(size_t)d * T_ + p];
  }
  __syncthreads();

  // per-point ||x||^2 in fp64 (64 threads)
  if (tid < 64) {
    double s = 0.0;
    for (int d = 0; d < 256; ++d) {
      double v = (double)xs[d * 64 + tid];
      s += v * v;
    }
    xn2[tid] = s;
  }
  // (ordered before use by the barriers inside the chunk loop)

  int ptg = tid >> 4;              // 0..15 -> 4 points each
  int cg = tid & 15;               // 0..15 -> 8 codes each
  int p0 = ptg * 4;
  int c0 = cg * 8;

  float best[4] = {1e30f, 1e30f, 1e30f, 1e30f};
  int bidx[4] = {0, 0, 0, 0};

  for (int ct = 0; ct < 8; ++ct) {   // code tiles of 128
    int cb = ct * 128;
    float tot[4][8];
#pragma unroll
    for (int i = 0; i < 4; ++i)
#pragma unroll
      for (int jj = 0; jj < 8; ++jj) tot[i][jj] = 0.0f;

    for (int dc = 0; dc < 16; ++dc) {  // 16 chunks of 16 d
      int d0 = dc * 16;
      __syncthreads();
      // stage es[16][128] from embedT (coalesced)
#pragma unroll
      for (int i = 0; i < 8; ++i) {
        int fl = i * 256 + tid;
        int dd = fl >> 7;
        int c = fl & 127;
        es[dd * 128 + c] = embedT[(size_t)(d0 + dd) * NC_ + cb + c];
      }
      __syncthreads();

      float ch[4][8];
#pragma unroll
      for (int i = 0; i < 4; ++i)
#pragma unroll
        for (int jj = 0; jj < 8; ++jj) ch[i][jj] = 0.0f;

#pragma unroll
      for (int dd = 0; dd < 16; ++dd) {
        const float4 xv = *(const float4*)(xs + (d0 + dd) * 64 + p0);
        const float4 e0 = *(const float4*)(es + dd * 128 + c0);
        const float4 e1 = *(const float4*)(es + dd * 128 + c0 + 4);
        float xa[4] = {xv.x, xv.y, xv.z, xv.w};
        float eb[8] = {e0.x, e0.y, e0.z, e0.w, e1.x, e1.y, e1.z, e1.w};
#pragma unroll
        for (int i = 0; i < 4; ++i)
#pragma unroll
          for (int jj = 0; jj < 8; ++jj)
            ch[i][jj] = fmaf(xa[i], eb[jj], ch[i][jj]);
      }
#pragma unroll
      for (int i = 0; i < 4; ++i)
#pragma unroll
        for (int jj = 0; jj < 8; ++jj) tot[i][jj] += ch[i][jj];
    }

    // fold this code tile into the running argmin (fp64 combine, fp32 compare
    // with lower-index tie-break to mimic np semantics)
#pragma unroll
    for (int jj = 0; jj < 8; ++jj) {
      int cidx = cb + c0 + jj;
      double nrm = norms[cidx];
#pragma unroll
      for (int i = 0; i < 4; ++i) {
        double dist = xn2[p0 + i] + nrm - 2.0 * (double)tot[i][jj];
        float df = (float)dist;
        if (df < best[i] || (df == best[i] && cidx < bidx[i])) {
          best[i] = df;
          bidx[i] = cidx;
        }
      }
    }
  }

  // cross-thread reduce over the 16 code-groups (consecutive lanes in a wave)
#pragma unroll
  for (int m = 1; m < 16; m <<= 1) {
#pragma unroll
    for (int i = 0; i < 4; ++i) {
      float ov = __shfl_xor(best[i], m, 64);
      int oi = __shfl_xor(bidx[i], m, 64);
      if (ov < best[i] || (ov == best[i] && oi < bidx[i])) {
        best[i] = ov;
        bidx[i] = oi;
      }
    }
  }

  if (cg == 0) {
#pragma unroll
    for (int i = 0; i < 4; ++i) {
      int n = b * T_ + t0 + p0 + i;
      idx_out[n] = (float)bidx[i];
      atomicAdd(&counts[bidx[i]], 1);
    }
  }
}

// ---------------- Kernel C: gather quantized + MSE + coalesced write --------
__global__ __launch_bounds__(256, 2) void quantize_kernel(
    const float* __restrict__ inputs, const float* __restrict__ embed,
    const float* __restrict__ idx_f, float* __restrict__ qout,
    double* __restrict__ mse_acc) {
  __shared__ float qs[64 * 257];   // [p][d], pad 257 -> conflict-free
  __shared__ int lidx[64];
  __shared__ double red[4];

  int tid = threadIdx.x;
  int bx = blockIdx.x;
  int b = bx >> 4;
  int t0 = (bx & 15) * 64;

  if (tid < 64) lidx[tid] = (int)idx_f[b * T_ + t0 + tid];
  __syncthreads();

  // build q tile: one point per iteration, 256 lanes over d (coalesced)
#pragma unroll 4
  for (int p = 0; p < 64; ++p) {
    qs[p * 257 + tid] = embed[(size_t)lidx[p] * D_ + tid];
  }
  __syncthreads();

  double acc = 0.0;
  size_t base = (size_t)b * DT_ + t0;
#pragma unroll 4
  for (int i = 0; i < 64; ++i) {
    int d = i * 4 + (tid >> 6);
    int p = tid & 63;
    float x = inputs[base + (size_t)d * T_ + p];
    float q = qs[p * 257 + d];
    float diff = q - x;
    acc += (double)diff * (double)diff;
    qout[base + (size_t)d * T_ + p] = q;
  }

  for (int m = 32; m; m >>= 1) acc += __shfl_down(acc, m, 64);
  if ((tid & 63) == 0) red[tid >> 6] = acc;
  __syncthreads();
  if (tid == 0) atomicAdd(mse_acc, red[0] + red[1] + red[2] + red[3]);
}

// ---------------- Kernel D: finalize scalars --------------------------------
__global__ void finalize_kernel(const int* __restrict__ counts,
                                const double* __restrict__ mse_acc,
                                float* __restrict__ out) {
  int tid = threadIdx.x;  // 1024
  double p = (double)counts[tid] / (double)NPTS_;
  double term = p * log(p + 1e-10);
  double s = term;
  for (int m = 32; m; m >>= 1) s += __shfl_down(s, m, 64);
  __shared__ double red[16];
  if ((tid & 63) == 0) red[tid >> 6] = s;
  __syncthreads();
  if (tid == 0) {
    double tot = 0.0;
    for (int i = 0; i < 16; ++i) tot += red[i];
    double mse = *mse_acc / (double)QSZ_;
    out[LOSS_OFF] = (float)(mse * 1.2);
    out[CMT_OFF] = (float)mse;
    out[PERP_OFF] = (float)exp(-tot);
  }
}

// ---------------- launch ----------------------------------------------------
extern "C" void kernel_launch(void* const* d_in, const int* in_sizes, int n_in,
                              void* d_out, int out_size, void* d_ws,
                              size_t ws_size, hipStream_t stream) {
  const float* inputs = (const float*)d_in[0];
  const float* embed = (const float*)d_in[1];
  float* out = (float*)d_out;

  char* ws = (char*)d_ws;
  float* embedT = (float*)ws;                              // 1,048,576 B
  double* norms = (double*)(ws + 1048576);                 // 8,192 B
  int* counts = (int*)(ws + 1048576 + 8192);               // 4,096 B
  double* mse = (double*)(ws + 1048576 + 8192 + 4096);     // 8 B

  // zero the accumulators (counts + mse) every launch
  hipMemsetAsync(ws + 1048576 + 8192, 0, 4096 + 8, stream);

  prep_kernel<<<NC_, 256, 0, stream>>>(embed, embedT, norms);
  argmin_kernel<<<1024, 256, 0, stream>>>(inputs, embedT, norms,
                                          out + IDX_OFF, counts);
  quantize_kernel<<<1024, 256, 0, stream>>>(inputs, embed, out + IDX_OFF, out,
                                            mse);
  finalize_kernel<<<1, 1024, 0, stream>>>(counts, mse, out);
}

// Round 2
// 166.959 us; speedup vs baseline: 3.9079x; 3.9079x over previous
//
#include <hip/hip_runtime.h>

#define B_ 64
#define D_ 256
#define T_ 1024
#define NC_ 1024
#define DT_ (D_ * T_)              // 262144
#define NPTS_ (B_ * T_)            // 65536

#define QSZ_   16777216            // B*D*T
#define LOSS_OFF 16777216
#define CMT_OFF  16777217
#define IDX_OFF  16777218
#define PERP_OFF 16842754

typedef _Float16 half8 __attribute__((ext_vector_type(8)));
typedef float f32x4 __attribute__((ext_vector_type(4)));

// LDS row stride for x tiles: 256 k + 8 pad halves = 264 (528B = 33*16, keeps
// 16B alignment for ds_read_b128; rows land 2-way on banks = free)
#define XROW_ 264
#define XLO_OFF_ (64 * XROW_)      // xs_lo starts here (halfs)

// ---------------- Kernel P: split embed into frag-order hi/lo + fp64 norms --
// ehi/elo layout: frag-major. For code-group g (16 codes), k-chunk kc (32 k),
// lane l: element j holds e[g*16 + (l&15)][kc*32 + (l>>4)*8 + j].
// Stored at half-offset ((g*8 + kc)*64 + l)*8 + j  -> wave loads 1KB contiguous.
__global__ void prep_embed(const float* __restrict__ embed,
                           _Float16* __restrict__ ehi,
                           _Float16* __restrict__ elo,
                           double* __restrict__ norms) {
  int g = blockIdx.x;              // 64 blocks
  int tid = threadIdx.x;           // 256
  int w = tid >> 6, l = tid & 63;

#pragma unroll
  for (int ii = 0; ii < 2; ++ii) {
    int kc = w * 2 + ii;
    int code = g * 16 + (l & 15);
    int k0 = kc * 32 + (l >> 4) * 8;
    const float* src = embed + (size_t)code * D_ + k0;
    half8 hh, ll;
#pragma unroll
    for (int j = 0; j < 8; ++j) {
      float v = src[j];
      _Float16 h = (_Float16)v;
      _Float16 lo = (_Float16)(v - (float)h);
      hh[j] = h;
      ll[j] = lo;
    }
    size_t off = ((size_t)(g * 8 + kc) * 64 + l) * 8;
    *(half8*)(ehi + off) = hh;
    *(half8*)(elo + off) = ll;
  }

  // fp64 norms: thread -> (code = g*16 + tid>>4, k-segment (tid&15)*16)
  int code = g * 16 + (tid >> 4);
  int ks = (tid & 15) * 16;
  const float* src = embed + (size_t)code * D_ + ks;
  double s = 0.0;
#pragma unroll
  for (int j = 0; j < 16; ++j) {
    double v = src[j];
    s += v * v;
  }
#pragma unroll
  for (int m = 1; m < 16; m <<= 1) s += __shfl_xor(s, m, 64);
  if ((tid & 15) == 0) norms[code] = s;
}

// ---------------- Kernel B: MFMA distance GEMM + argmin ---------------------
// 1024 blocks x 256 threads (4 waves). Block owns 64 points (one b, 64 t).
// x tile staged once in LDS as f16 hi/lo (pad-264 rows). Each wave covers 64
// codes per ng-iteration (4 N-frags), 4 ng iterations -> 256 codes/wave.
// Per (ng,kc): 8 A ds_read_b128 + 8 B global b128 + 48 MFMA. No barriers in
// the main loop.
__global__ __launch_bounds__(256, 2) void argmin_kernel(
    const float* __restrict__ inputs, const _Float16* __restrict__ ehi,
    const _Float16* __restrict__ elo, const double* __restrict__ norms,
    float* __restrict__ idx_out, int* __restrict__ counts,
    double* __restrict__ mse_acc) {
  __shared__ _Float16 xs[2 * 64 * XROW_];  // hi then lo, 67.6 KB
  __shared__ double part[256];
  __shared__ double xn2s[64];
  __shared__ float candv[4][64];
  __shared__ int candi[4][64];

  int tid = threadIdx.x;
  int blk = blockIdx.x;            // point block: 64 points
  int b = blk >> 4, t0 = (blk & 15) * 64;
  size_t base = (size_t)b * DT_ + t0;

  // ---- stage x tile: f32 -> (hi,lo) f16, transpose [d][t] -> [t][k=d] ----
  {
    int t = tid & 63, dgrp = tid >> 6;
    const float* src = inputs + base + t;
    double s = 0.0;
#pragma unroll 4
    for (int i = 0; i < 32; ++i) {
      int d = dgrp * 64 + i * 2;
      float v0 = src[(size_t)d * T_];
      float v1 = src[(size_t)(d + 1) * T_];
      s += (double)v0 * v0 + (double)v1 * v1;
      _Float16 h0 = (_Float16)v0, h1 = (_Float16)v1;
      _Float16 e0 = (_Float16)(v0 - (float)h0);
      _Float16 e1 = (_Float16)(v1 - (float)h1);
      union {
        _Float16 h[2];
        unsigned u;
      } ph, pl;
      ph.h[0] = h0; ph.h[1] = h1;
      pl.h[0] = e0; pl.h[1] = e1;
      *(unsigned*)&xs[t * XROW_ + d] = ph.u;
      *(unsigned*)&xs[XLO_OFF_ + t * XROW_ + d] = pl.u;
    }
    part[tid] = s;
  }
  __syncthreads();
  if (tid < 64)
    xn2s[tid] = part[tid] + part[64 + tid] + part[128 + tid] + part[192 + tid];
  __syncthreads();

  int w = tid >> 6, l = tid & 63;
  int lrow = l & 15;
  int lk = (l >> 4) * 8;

  // per-lane point slots: p_local = m*16 + (l>>4)*4 + r
  float bestv[4][4];
  int besti[4][4];
#pragma unroll
  for (int m = 0; m < 4; ++m)
#pragma unroll
    for (int r = 0; r < 4; ++r) {
      bestv[m][r] = 1e30f;
      besti[m][r] = 0;
    }

  for (int ng = 0; ng < 4; ++ng) {
    f32x4 acc[4][4];
#pragma unroll
    for (int m = 0; m < 4; ++m)
#pragma unroll
      for (int n = 0; n < 4; ++n) acc[m][n] = (f32x4){0.f, 0.f, 0.f, 0.f};

#pragma unroll 2
    for (int kc = 0; kc < 8; ++kc) {
      half8 ah[4], al[4];
#pragma unroll
      for (int m = 0; m < 4; ++m) {
        const _Float16* p = &xs[(m * 16 + lrow) * XROW_ + kc * 32 + lk];
        ah[m] = *(const half8*)p;
        al[m] = *(const half8*)(p + XLO_OFF_);
      }
      half8 bh[4], bl[4];
#pragma unroll
      for (int n = 0; n < 4; ++n) {
        int g = ng * 16 + w * 4 + n;
        size_t off = ((size_t)(g * 8 + kc) * 64 + l) * 8;
        bh[n] = *(const half8*)(ehi + off);
        bl[n] = *(const half8*)(elo + off);
      }
#pragma unroll
      for (int m = 0; m < 4; ++m)
#pragma unroll
        for (int n = 0; n < 4; ++n) {
          acc[m][n] =
              __builtin_amdgcn_mfma_f32_16x16x32_f16(ah[m], bh[n], acc[m][n], 0, 0, 0);
          acc[m][n] =
              __builtin_amdgcn_mfma_f32_16x16x32_f16(al[m], bh[n], acc[m][n], 0, 0, 0);
          acc[m][n] =
              __builtin_amdgcn_mfma_f32_16x16x32_f16(ah[m], bl[n], acc[m][n], 0, 0, 0);
        }
    }

    // fold into running argmin (fp64 combine, fp32 binning, low-index ties)
#pragma unroll
    for (int n = 0; n < 4; ++n) {
      int c = ng * 256 + w * 64 + n * 16 + lrow;
      double nrm = norms[c];
#pragma unroll
      for (int m = 0; m < 4; ++m) {
        double x2_0 = xn2s[m * 16 + (l >> 4) * 4 + 0];  // broadcast reads
#pragma unroll
        for (int r = 0; r < 4; ++r) {
          double x2 = xn2s[m * 16 + (l >> 4) * 4 + r];
          double dist = x2 + nrm - 2.0 * (double)acc[m][n][r];
          float df = (float)dist;
          if (df < bestv[m][r] || (df == bestv[m][r] && c < besti[m][r])) {
            bestv[m][r] = df;
            besti[m][r] = c;
          }
        }
        (void)x2_0;
      }
    }
  }

  // reduce across the 16 code-lanes of each quarter
#pragma unroll
  for (int msk = 1; msk < 16; msk <<= 1) {
#pragma unroll
    for (int m = 0; m < 4; ++m)
#pragma unroll
      for (int r = 0; r < 4; ++r) {
        float ov = __shfl_xor(bestv[m][r], msk, 64);
        int oi = __shfl_xor(besti[m][r], msk, 64);
        if (ov < bestv[m][r] || (ov == bestv[m][r] && oi < besti[m][r])) {
          bestv[m][r] = ov;
          besti[m][r] = oi;
        }
      }
  }
  if (lrow == 0) {
    int q = l >> 4;
#pragma unroll
    for (int m = 0; m < 4; ++m)
#pragma unroll
      for (int r = 0; r < 4; ++r) {
        candv[w][m * 16 + q * 4 + r] = bestv[m][r];
        candi[w][m * 16 + q * 4 + r] = besti[m][r];
      }
  }
  __syncthreads();

  if (tid < 64) {
    float bv = candv[0][tid];
    int bi = candi[0][tid];
#pragma unroll
    for (int w2 = 1; w2 < 4; ++w2) {
      float ov = candv[w2][tid];
      int oi = candi[w2][tid];
      if (ov < bv || (ov == bv && oi < bi)) {
        bv = ov;
        bi = oi;
      }
    }
    int p = blk * 64 + tid;
    idx_out[p] = (float)bi;
    atomicAdd(&counts[bi], 1);
    // MSE = sum of min distances (dist = ||x - e||^2)
    double s = (double)bv;
    for (int msk = 32; msk; msk >>= 1) s += __shfl_down(s, msk, 64);
    if (tid == 0) atomicAdd(mse_acc, s);
  }
}

// ---------------- Kernel C: gather quantized rows, coalesced write ----------
__global__ __launch_bounds__(256) void quantize_kernel(
    const float* __restrict__ embed, const float* __restrict__ idx_f,
    float* __restrict__ qout) {
  __shared__ float qs[64 * 257];
  __shared__ int lidx[64];

  int tid = threadIdx.x;
  int bx = blockIdx.x;
  int b = bx >> 4;
  int t0 = (bx & 15) * 64;

  if (tid < 64) lidx[tid] = (int)idx_f[b * T_ + t0 + tid];
  __syncthreads();

#pragma unroll 4
  for (int p = 0; p < 64; ++p) {
    qs[p * 257 + tid] = embed[(size_t)lidx[p] * D_ + tid];
  }
  __syncthreads();

  size_t base = (size_t)b * DT_ + t0;
#pragma unroll 4
  for (int i = 0; i < 64; ++i) {
    int d = i * 4 + (tid >> 6);
    int p = tid & 63;
    qout[base + (size_t)d * T_ + p] = qs[p * 257 + d];
  }
}

// ---------------- Kernel D: finalize scalars --------------------------------
__global__ void finalize_kernel(const int* __restrict__ counts,
                                const double* __restrict__ mse_acc,
                                float* __restrict__ out) {
  int tid = threadIdx.x;  // 1024
  double p = (double)counts[tid] / (double)NPTS_;
  double s = p * log(p + 1e-10);
  for (int m = 32; m; m >>= 1) s += __shfl_down(s, m, 64);
  __shared__ double red[16];
  if ((tid & 63) == 0) red[tid >> 6] = s;
  __syncthreads();
  if (tid == 0) {
    double tot = 0.0;
    for (int i = 0; i < 16; ++i) tot += red[i];
    double mse = *mse_acc / (double)QSZ_;
    out[LOSS_OFF] = (float)(mse * 1.2);
    out[CMT_OFF] = (float)mse;
    out[PERP_OFF] = (float)exp(-tot);
  }
}

// ---------------- launch ----------------------------------------------------
extern "C" void kernel_launch(void* const* d_in, const int* in_sizes, int n_in,
                              void* d_out, int out_size, void* d_ws,
                              size_t ws_size, hipStream_t stream) {
  const float* inputs = (const float*)d_in[0];
  const float* embed = (const float*)d_in[1];
  float* out = (float*)d_out;

  char* ws = (char*)d_ws;
  _Float16* ehi = (_Float16*)ws;                         // 512 KB
  _Float16* elo = (_Float16*)(ws + 524288);              // 512 KB
  double* norms = (double*)(ws + 1048576);               // 8 KB
  int* counts = (int*)(ws + 1048576 + 8192);             // 4 KB
  double* mse = (double*)(ws + 1048576 + 8192 + 4096);   // 8 B

  hipMemsetAsync(ws + 1048576 + 8192, 0, 4096 + 8, stream);

  prep_embed<<<64, 256, 0, stream>>>(embed, ehi, elo, norms);
  argmin_kernel<<<1024, 256, 0, stream>>>(inputs, ehi, elo, norms,
                                          out + IDX_OFF, counts, mse);
  quantize_kernel<<<1024, 256, 0, stream>>>(embed, out + IDX_OFF, out);
  finalize_kernel<<<1, 1024, 0, stream>>>(counts, mse, out);
}